// Round 3
// baseline (824.047 us; speedup 1.0000x reference)
//
#include <hip/hip_runtime.h>

typedef unsigned short u16;
typedef unsigned int u32;
typedef __attribute__((ext_vector_type(4))) float f32x4;
typedef __attribute__((ext_vector_type(8))) __bf16 bf16x8;
typedef __attribute__((ext_vector_type(4))) u16 u16x4;

#define NB 2
#define NS 2048
#define ND 1024
#define NH 16
#define NHD 64
#define NFF 4096
#define NBS (NB * NS)   // 4096 rows

typedef const __attribute__((address_space(1))) unsigned int as1_u32;
typedef __attribute__((address_space(3))) unsigned int as3_u32;

__device__ __forceinline__ void gl_lds16(const u16* g, u16* l) {
  __builtin_amdgcn_global_load_lds((as1_u32*)g, (as3_u32*)l, 16, 0, 0);
}

__device__ __forceinline__ u16 f2bf(float f) {
  union { float f; unsigned u; } v; v.f = f;
  unsigned r = (v.u + 0x7FFFu + ((v.u >> 16) & 1u)) >> 16;  // RNE
  return (u16)r;
}

// ---------------- f32 -> bf16 (vectorized) ----------------
__global__ __launch_bounds__(256) void conv_bf16(const float* __restrict__ in,
                                                 u16* __restrict__ out, int n4) {
  int i = blockIdx.x * 256 + threadIdx.x;
  if (i >= n4) return;
  f32x4 v = *reinterpret_cast<const f32x4*>(&in[(size_t)i * 4]);
  u16x4 o;
#pragma unroll
  for (int j = 0; j < 4; ++j) o[j] = f2bf(v[j]);
  *reinterpret_cast<u16x4*>(&out[(size_t)i * 4]) = o;
}

// ---------------- weight convert + transpose: [K,N] f32 -> [N,K] bf16 ----------------
__global__ void wconv_t(const float* __restrict__ in, u16* __restrict__ out, int K, int N) {
  __shared__ float t[32][33];
  int n0 = blockIdx.x * 32, k0 = blockIdx.y * 32;
  int tx = threadIdx.x, ty = threadIdx.y;  // 32 x 8
#pragma unroll
  for (int i = ty; i < 32; i += 8) t[i][tx] = in[(size_t)(k0 + i) * N + n0 + tx];
  __syncthreads();
#pragma unroll
  for (int i = ty; i < 32; i += 8)
    out[(size_t)(n0 + i) * K + k0 + tx] = f2bf(t[tx][i]);
}

// ---------------- GEMM (m97 structure): global_load_lds staging, linear LDS ----------------
// C[M,N] = A[M,K](bf16) @ BT[N,K]^T(bf16) + bias. 128x128 tile, BK=32, 4 waves 64x64.
template <int OUTF32, int RELU>
__global__ __launch_bounds__(256) void gemm_bt(const u16* __restrict__ A,
                                               const u16* __restrict__ BT,
                                               const float* __restrict__ bias,
                                               float* __restrict__ Cf,
                                               u16* __restrict__ Cb,
                                               int M, int N, int K) {
  __shared__ __align__(16) u16 lA[128 * 32];
  __shared__ __align__(16) u16 lB[128 * 32];
  const int tid = threadIdx.x;
  const int lane = tid & 63, wave = tid >> 6;
  const int bm = blockIdx.y * 128, bn = blockIdx.x * 128;
  const int wr = (wave >> 1) * 64, wc = (wave & 1) * 64;
  const int r16 = lane & 15, kg = lane >> 4;

  f32x4 acc[4][4] = {};

  for (int k0 = 0; k0 < K; k0 += 32) {
    __syncthreads();
#pragma unroll
    for (int c = 0; c < 2; ++c) {
      int chunk = c * 256 + tid;
      int r = chunk >> 2, kc = (chunk & 3) * 8;
      // LDS dest: wave-uniform base + lane*16B == chunk*16B (linear layout required)
      gl_lds16(&A[(size_t)(bm + r) * K + k0 + kc], &lA[(size_t)(c * 256 + wave * 64) * 8]);
      gl_lds16(&BT[(size_t)(bn + r) * K + k0 + kc], &lB[(size_t)(c * 256 + wave * 64) * 8]);
    }
    __syncthreads();

    bf16x8 af[4], bfr[4];
#pragma unroll
    for (int m = 0; m < 4; ++m)
      af[m] = *reinterpret_cast<const bf16x8*>(&lA[(wr + m * 16 + r16) * 32 + kg * 8]);
#pragma unroll
    for (int n = 0; n < 4; ++n)
      bfr[n] = *reinterpret_cast<const bf16x8*>(&lB[(wc + n * 16 + r16) * 32 + kg * 8]);
#pragma unroll
    for (int m = 0; m < 4; ++m)
#pragma unroll
      for (int n = 0; n < 4; ++n)
        acc[m][n] = __builtin_amdgcn_mfma_f32_16x16x32_bf16(af[m], bfr[n], acc[m][n], 0, 0, 0);
  }

#pragma unroll
  for (int m = 0; m < 4; ++m) {
    int row = bm + wr + m * 16 + kg * 4;
#pragma unroll
    for (int n = 0; n < 4; ++n) {
      int col = bn + wc + n * 16 + r16;
      float bv = bias[col];
#pragma unroll
      for (int j = 0; j < 4; ++j) {
        float v = acc[m][n][j] + bv;
        if (RELU) v = fmaxf(v, 0.f);
        if (OUTF32)
          Cf[(size_t)(row + j) * N + col] = v;
        else
          Cb[(size_t)(row + j) * N + col] = f2bf(v);
      }
    }
  }
}

// ---------------- V transpose: gather V columns from GEMM output -> VT[bh][64][S] ----------------
__global__ __launch_bounds__(256) void vt_kern(const u16* __restrict__ src, int stride,
                                               int hmul, int hadd, u16* __restrict__ VT) {
  const int bh = blockIdx.y;
  const int b = bh >> 4, h = bh & 15;
  const int s0 = blockIdx.x * 32;
  const int t = threadIdx.x;
  const int d = t >> 2, sg = t & 3;
  const u16* sb = src + (size_t)b * NS * stride + h * hmul + hadd + d;
  union { u16 e[8]; uint4 v; } pk;
#pragma unroll
  for (int i = 0; i < 8; ++i)
    pk.e[i] = sb[(size_t)(s0 + sg * 8 + i) * stride];
  *reinterpret_cast<uint4*>(&VT[((size_t)bh * NHD + d) * NS + s0 + sg * 8]) = pk.v;
}

// ---------------- flash attention v3: 16 q-rows/wave, barrier-free, swapped QK^T ----------------
// 1024 blocks x 4 waves = 4096 waves (16/CU). Heavy-first qt order for causal balance.
// S^T = mfma(Kfrag, Qfrag): lane holds col q = r16, rows kv = c*16+kg*4+j.
#define LPP 72  // P row pitch (u16)

template <int CAUSAL>
__global__ __launch_bounds__(256) void attn3(const u16* __restrict__ Qp, int qstride, int qhm,
                                             const u16* __restrict__ Kp, int kstride, int khm,
                                             int kha, const u16* __restrict__ VT,
                                             u16* __restrict__ O) {
  const int bid = blockIdx.x;                 // 1024
  const int xcd = bid & 7, j7 = bid >> 3;     // j7: 0..127
  const int bh = xcd + 8 * (j7 >> 5);         // 4 bh per XCD -> K/VT pinned in one L2
  int qt = j7 & 31;
  if (CAUSAL) qt = 31 - qt;                   // heavy blocks dispatch first
  const int b = bh >> 4, h = bh & 15;
  const int tid = threadIdx.x, lane = tid & 63, wave = tid >> 6;
  const int r16 = lane & 15, kg = lane >> 4;
  const int q0w = qt * 64 + wave * 16;
  const float scale = 0.125f;

  __shared__ __align__(16) u16 lP[4][16 * LPP];   // wave-private P tiles
  u16* lPw = &lP[wave][0];

  const u16* qb = Qp + (size_t)b * NS * qstride + h * qhm;
  const u16* kb = Kp + (size_t)b * NS * kstride + h * khm + kha;
  const u16* vb = VT + (size_t)bh * NHD * NS;

  bf16x8 qf[2];
#pragma unroll
  for (int ks = 0; ks < 2; ++ks)
    qf[ks] = *reinterpret_cast<const bf16x8*>(
        &qb[(size_t)(q0w + r16) * qstride + ks * 32 + kg * 8]);

  f32x4 o_acc[4] = {};
  float m_run = -1e30f, l_run = 0.f;

  const int nt = CAUSAL ? (qt + 1) : (NS / 64);
  for (int t = 0; t < nt; ++t) {
    const int kv0 = t * 64;

    // ---- K frags (8 loads issued together), then S^T MFMAs ----
    bf16x8 kf[8];
#pragma unroll
    for (int c = 0; c < 4; ++c)
#pragma unroll
      for (int ks = 0; ks < 2; ++ks)
        kf[c * 2 + ks] = *reinterpret_cast<const bf16x8*>(
            &kb[(size_t)(kv0 + c * 16 + r16) * kstride + ks * 32 + kg * 8]);
    f32x4 s[4] = {};
#pragma unroll
    for (int c = 0; c < 4; ++c)
#pragma unroll
      for (int ks = 0; ks < 2; ++ks)
        s[c] = __builtin_amdgcn_mfma_f32_16x16x32_bf16(kf[c * 2 + ks], qf[ks], s[c], 0, 0, 0);

    // ---- V frags issued early: latency hides under softmax ----
    bf16x8 vf[8];
#pragma unroll
    for (int cd = 0; cd < 4; ++cd)
#pragma unroll
      for (int ks = 0; ks < 2; ++ks)
        vf[cd * 2 + ks] = *reinterpret_cast<const bf16x8*>(
            &vb[(size_t)(cd * 16 + r16) * NS + kv0 + ks * 32 + kg * 8]);

    // ---- scale (+ mask only on the diagonal tile; wave-uniform branch) ----
    if (CAUSAL && t == nt - 1) {
      const int q = q0w + r16;
#pragma unroll
      for (int c = 0; c < 4; ++c)
#pragma unroll
        for (int j = 0; j < 4; ++j) {
          float v = s[c][j] * scale;
          if (kv0 + c * 16 + kg * 4 + j > q) v = -1e30f;
          s[c][j] = v;
        }
    } else {
#pragma unroll
      for (int c = 0; c < 4; ++c)
#pragma unroll
        for (int j = 0; j < 4; ++j) s[c][j] *= scale;
    }

    // ---- online softmax (q = r16 domain; m/l scalar per lane) ----
    float mx = fmaxf(fmaxf(fmaxf(s[0][0], s[0][1]), fmaxf(s[0][2], s[0][3])),
                     fmaxf(fmaxf(s[1][0], s[1][1]), fmaxf(s[1][2], s[1][3])));
    mx = fmaxf(mx, fmaxf(fmaxf(fmaxf(s[2][0], s[2][1]), fmaxf(s[2][2], s[2][3])),
                         fmaxf(fmaxf(s[3][0], s[3][1]), fmaxf(s[3][2], s[3][3]))));
    mx = fmaxf(mx, __shfl_xor(mx, 16));
    mx = fmaxf(mx, __shfl_xor(mx, 32));

    float mn, cr = 1.f;
    if (__all(mx <= m_run + 8.f)) {   // defer-max (T13): skip rescale, P bounded by e^8
      mn = m_run;
    } else {
      mn = fmaxf(m_run, mx);
      cr = __expf(m_run - mn);
      m_run = mn;
      float crow[4];
#pragma unroll
      for (int j = 0; j < 4; ++j) crow[j] = __shfl(cr, kg * 4 + j);
#pragma unroll
      for (int cd = 0; cd < 4; ++cd)
#pragma unroll
        for (int j = 0; j < 4; ++j) o_acc[cd][j] *= crow[j];
    }

    float su = 0.f;
#pragma unroll
    for (int c = 0; c < 4; ++c)
#pragma unroll
      for (int j = 0; j < 4; ++j) {
        float p = __expf(s[c][j] - mn);
        s[c][j] = p;
        su += p;
      }
    su += __shfl_xor(su, 16);
    su += __shfl_xor(su, 32);
    l_run = l_run * cr + su;

    // ---- P -> wave-private LDS (packed b32; no barrier) ----
#pragma unroll
    for (int c = 0; c < 4; ++c) {
      u32 u0 = (u32)f2bf(s[c][0]) | ((u32)f2bf(s[c][1]) << 16);
      u32 u1 = (u32)f2bf(s[c][2]) | ((u32)f2bf(s[c][3]) << 16);
      u16* row = &lPw[r16 * LPP + c * 16 + kg * 4];
      *reinterpret_cast<u32*>(row) = u0;
      *reinterpret_cast<u32*>(row + 2) = u1;
    }

    bf16x8 pf[2];
#pragma unroll
    for (int ks = 0; ks < 2; ++ks)
      pf[ks] = *reinterpret_cast<const bf16x8*>(&lPw[r16 * LPP + ks * 32 + kg * 8]);
#pragma unroll
    for (int cd = 0; cd < 4; ++cd)
#pragma unroll
      for (int ks = 0; ks < 2; ++ks)
        o_acc[cd] = __builtin_amdgcn_mfma_f32_16x16x32_bf16(pf[ks], vf[cd * 2 + ks],
                                                            o_acc[cd], 0, 0, 0);
  }

  // ---- epilogue: rows kg*4+j, cols h*64 + cd*16 + r16 ----
  float linv = 1.f / l_run;
  float li[4];
#pragma unroll
  for (int j = 0; j < 4; ++j) li[j] = __shfl(linv, kg * 4 + j);
#pragma unroll
  for (int cd = 0; cd < 4; ++cd) {
    int col = h * NHD + cd * 16 + r16;
#pragma unroll
    for (int j = 0; j < 4; ++j) {
      int row = q0w + kg * 4 + j;
      O[((size_t)b * NS + row) * ND + col] = f2bf(o_acc[cd][j] * li[j]);
    }
  }
}

// ---------------- fused residual + LayerNorm (writes f32 + bf16) ----------------
__global__ __launch_bounds__(256) void ln_kern(const float* __restrict__ a,
                                               const float* __restrict__ resid,
                                               const float* __restrict__ g,
                                               const float* __restrict__ bb,
                                               float* __restrict__ outf,
                                               u16* __restrict__ outb) {
  const int row = blockIdx.x;
  const int tid = threadIdx.x;
  const size_t off = (size_t)row * ND + tid * 4;
  f32x4 v = *reinterpret_cast<const f32x4*>(&a[off]);
  f32x4 r = *reinterpret_cast<const f32x4*>(&resid[off]);
#pragma unroll
  for (int j = 0; j < 4; ++j) v[j] += r[j];
  float s = v[0] + v[1] + v[2] + v[3];
  float s2 = v[0] * v[0] + v[1] * v[1] + v[2] * v[2] + v[3] * v[3];
#pragma unroll
  for (int m = 1; m < 64; m <<= 1) {
    s += __shfl_xor(s, m);
    s2 += __shfl_xor(s2, m);
  }
  __shared__ float ws1[4], ws2[4];
  int wave = tid >> 6, lane = tid & 63;
  if (lane == 0) { ws1[wave] = s; ws2[wave] = s2; }
  __syncthreads();
  s = ws1[0] + ws1[1] + ws1[2] + ws1[3];
  s2 = ws2[0] + ws2[1] + ws2[2] + ws2[3];
  float mean = s * (1.f / ND);
  float var = fmaxf(s2 * (1.f / ND) - mean * mean, 0.f);
  float rstd = rsqrtf(var + 1e-9f);
  f32x4 gg = *reinterpret_cast<const f32x4*>(&g[tid * 4]);
  f32x4 bv = *reinterpret_cast<const f32x4*>(&bb[tid * 4]);
  f32x4 o;
  u16x4 ob;
#pragma unroll
  for (int j = 0; j < 4; ++j) {
    o[j] = gg[j] * (v[j] - mean) * rstd + bv[j];
    ob[j] = f2bf(o[j]);
  }
  *reinterpret_cast<f32x4*>(&outf[off]) = o;
  *reinterpret_cast<u16x4*>(&outb[off]) = ob;
}

// ---------------- host launch ----------------
extern "C" void kernel_launch(void* const* d_in, const int* in_sizes, int n_in,
                              void* d_out, int out_size, void* d_ws, size_t ws_size,
                              hipStream_t stream) {
  const float* x = (const float*)d_in[0];
  const float* y = (const float*)d_in[1];
  const float* qkv_w = (const float*)d_in[3];
  const float* qkv_b = (const float*)d_in[4];
  const float* sa_fc_w = (const float*)d_in[5];
  const float* sa_fc_b = (const float*)d_in[6];
  const float* g1 = (const float*)d_in[7];
  const float* b1 = (const float*)d_in[8];
  const float* kv_w = (const float*)d_in[9];
  const float* kv_b = (const float*)d_in[10];
  const float* q_w = (const float*)d_in[11];
  const float* q_b = (const float*)d_in[12];
  const float* ca_fc_w = (const float*)d_in[13];
  const float* ca_fc_b = (const float*)d_in[14];
  const float* g2 = (const float*)d_in[15];
  const float* b2 = (const float*)d_in[16];
  const float* ff1_w = (const float*)d_in[17];
  const float* ff1_b = (const float*)d_in[18];
  const float* ff2_w = (const float*)d_in[19];
  const float* ff2_b = (const float*)d_in[20];
  const float* g3 = (const float*)d_in[21];
  const float* b3 = (const float*)d_in[22];

  if (ws_size < (120ull << 20)) return;

  char* w = (char*)d_ws;
  u16* W16 = (u16*)(w + 0);              // 8 MB
  u16* ACT = (u16*)(w + (8ull << 20));   // 8 MB
  u16* XB  = (u16*)(w + (16ull << 20));  // 8 MB
  u16* Qb  = (u16*)(w + (24ull << 20));  // 8 MB (cross-attn Q gemm out)
  u16* VT  = (u16*)(w + (40ull << 20));  // 8 MB (V transposed [bh][64][S])
  u16* AO  = (u16*)(w + (48ull << 20));  // 8 MB attention out
  u16* G   = (u16*)(w + (56ull << 20));  // 24 MB big GEMM out
  float* Fa = (float*)(w + (88ull << 20));   // 16 MB
  float* Fb = (float*)(w + (104ull << 20));  // 16 MB
  float* OUT = (float*)d_out;

  dim3 wblk(32, 8);
  const int n4act = NBS * ND / 4;

  // ---- self attention block ----
  conv_bf16<<<n4act / 256, 256, 0, stream>>>(y, ACT, n4act);
  wconv_t<<<dim3(3 * ND / 32, ND / 32), wblk, 0, stream>>>(qkv_w, W16, ND, 3 * ND);
  gemm_bt<0, 0><<<dim3(3 * ND / 128, NBS / 128), 256, 0, stream>>>(
      ACT, W16, qkv_b, nullptr, G, NBS, 3 * ND, ND);
  vt_kern<<<dim3(NS / 32, NB * NH), 256, 0, stream>>>(G, 3 * ND, 192, 128, VT);
  attn3<1><<<1024, 256, 0, stream>>>(G, 3 * ND, 192, G, 3 * ND, 192, 64, VT, AO);
  wconv_t<<<dim3(ND / 32, ND / 32), wblk, 0, stream>>>(sa_fc_w, W16, ND, ND);
  gemm_bt<1, 0><<<dim3(ND / 128, NBS / 128), 256, 0, stream>>>(
      AO, W16, sa_fc_b, Fa, nullptr, NBS, ND, ND);
  ln_kern<<<NBS, 256, 0, stream>>>(Fa, y, g1, b1, Fb, ACT);  // y1

  // ---- cross attention block ----
  conv_bf16<<<n4act / 256, 256, 0, stream>>>(x, XB, n4act);
  wconv_t<<<dim3(2 * ND / 32, ND / 32), wblk, 0, stream>>>(kv_w, W16, ND, 2 * ND);
  gemm_bt<0, 0><<<dim3(2 * ND / 128, NBS / 128), 256, 0, stream>>>(
      XB, W16, kv_b, nullptr, G, NBS, 2 * ND, ND);
  vt_kern<<<dim3(NS / 32, NB * NH), 256, 0, stream>>>(G, 2 * ND, 128, 64, VT);
  wconv_t<<<dim3(ND / 32, ND / 32), wblk, 0, stream>>>(q_w, W16, ND, ND);
  gemm_bt<0, 0><<<dim3(ND / 128, NBS / 128), 256, 0, stream>>>(
      ACT, W16, q_b, nullptr, Qb, NBS, ND, ND);
  attn3<0><<<1024, 256, 0, stream>>>(Qb, ND, 64, G, 2 * ND, 128, 0, VT, AO);
  wconv_t<<<dim3(ND / 32, ND / 32), wblk, 0, stream>>>(ca_fc_w, W16, ND, ND);
  gemm_bt<1, 0><<<dim3(ND / 128, NBS / 128), 256, 0, stream>>>(
      AO, W16, ca_fc_b, Fa, nullptr, NBS, ND, ND);
  ln_kern<<<NBS, 256, 0, stream>>>(Fa, Fb, g2, b2, Fb, ACT);  // y2

  // ---- FFN ----
  wconv_t<<<dim3(NFF / 32, ND / 32), wblk, 0, stream>>>(ff1_w, W16, ND, NFF);
  gemm_bt<0, 1><<<dim3(NFF / 128, NBS / 128), 256, 0, stream>>>(
      ACT, W16, ff1_b, nullptr, G, NBS, NFF, ND);
  wconv_t<<<dim3(ND / 32, NFF / 32), wblk, 0, stream>>>(ff2_w, W16, NFF, ND);
  gemm_bt<1, 0><<<dim3(ND / 128, NBS / 128), 256, 0, stream>>>(
      G, W16, ff2_b, Fa, nullptr, NBS, ND, NFF);
  ln_kern<<<NBS, 256, 0, stream>>>(Fa, Fb, g3, b3, OUT, ACT);
}

// Round 4
// 554.071 us; speedup vs baseline: 1.4873x; 1.4873x over previous
//
#include <hip/hip_runtime.h>

typedef unsigned short u16;
typedef unsigned int u32;
typedef __attribute__((ext_vector_type(4))) float f32x4;
typedef __attribute__((ext_vector_type(8))) __bf16 bf16x8;
typedef __attribute__((ext_vector_type(4))) u16 u16x4;

#define NB 2
#define NS 2048
#define ND 1024
#define NH 16
#define NHD 64
#define NFF 4096
#define NBS (NB * NS)   // 4096 rows

typedef const __attribute__((address_space(1))) unsigned int as1_u32;
typedef __attribute__((address_space(3))) unsigned int as3_u32;

__device__ __forceinline__ void gl_lds16(const u16* g, u16* l) {
  __builtin_amdgcn_global_load_lds((as1_u32*)g, (as3_u32*)l, 16, 0, 0);
}

__device__ __forceinline__ u16 f2bf(float f) {
  union { float f; unsigned u; } v; v.f = f;
  unsigned r = (v.u + 0x7FFFu + ((v.u >> 16) & 1u)) >> 16;  // RNE
  return (u16)r;
}

// ---------------- f32 -> bf16 (vectorized) ----------------
__global__ __launch_bounds__(256) void conv_bf16(const float* __restrict__ in,
                                                 u16* __restrict__ out, int n4) {
  int i = blockIdx.x * 256 + threadIdx.x;
  if (i >= n4) return;
  f32x4 v = *reinterpret_cast<const f32x4*>(&in[(size_t)i * 4]);
  u16x4 o;
#pragma unroll
  for (int j = 0; j < 4; ++j) o[j] = f2bf(v[j]);
  *reinterpret_cast<u16x4*>(&out[(size_t)i * 4]) = o;
}

// ---------------- weight convert + transpose: [K,N] f32 -> [N,K] bf16 ----------------
__global__ void wconv_t(const float* __restrict__ in, u16* __restrict__ out, int K, int N) {
  __shared__ float t[32][33];
  int n0 = blockIdx.x * 32, k0 = blockIdx.y * 32;
  int tx = threadIdx.x, ty = threadIdx.y;  // 32 x 8
#pragma unroll
  for (int i = ty; i < 32; i += 8) t[i][tx] = in[(size_t)(k0 + i) * N + n0 + tx];
  __syncthreads();
#pragma unroll
  for (int i = ty; i < 32; i += 8)
    out[(size_t)(n0 + i) * K + k0 + tx] = f2bf(t[tx][i]);
}

// ---------------- GEMM, 2-phase double-buffered (T3 minimum) ----------------
// C[M,N] = A[M,K](bf16) @ BT[N,K]^T(bf16) + bias. Tile TM x 128, BK=32, 4 waves.
// stage(next) issued BEFORE compute(cur); single vmcnt-draining barrier per K-step.
template <int TM, int OUTF32, int RELU>
__global__ __launch_bounds__(256) void gemm_bt(const u16* __restrict__ A,
                                               const u16* __restrict__ BT,
                                               const float* __restrict__ bias,
                                               float* __restrict__ Cf,
                                               u16* __restrict__ Cb,
                                               int M, int N, int K) {
  constexpr int MR = TM / 32;        // m-frags per wave
  constexpr int ACH = TM / 64;       // A staging chunks
  __shared__ __align__(16) u16 lA[2][TM * 32];
  __shared__ __align__(16) u16 lB[2][128 * 32];
  const int tid = threadIdx.x;
  const int lane = tid & 63, wave = tid >> 6;
  const int bm = blockIdx.y * TM, bn = blockIdx.x * 128;
  const int wr = (wave >> 1) * (MR * 16), wc = (wave & 1) * 64;
  const int r16 = lane & 15, kg = lane >> 4;

  f32x4 acc[MR][4] = {};

  auto stage = [&](int buf, int k0) {
#pragma unroll
    for (int c = 0; c < ACH; ++c) {
      int chunk = c * 256 + tid;
      int r = chunk >> 2, kc = (chunk & 3) * 8;
      gl_lds16(&A[(size_t)(bm + r) * K + k0 + kc], &lA[buf][(c * 256 + wave * 64) * 8]);
    }
#pragma unroll
    for (int c = 0; c < 2; ++c) {
      int chunk = c * 256 + tid;
      int r = chunk >> 2, kc = (chunk & 3) * 8;
      gl_lds16(&BT[(size_t)(bn + r) * K + k0 + kc], &lB[buf][(c * 256 + wave * 64) * 8]);
    }
  };

  stage(0, 0);
  __syncthreads();  // drains vmcnt of stage(0)

  const int nk = K / 32;
  for (int i = 0; i < nk; ++i) {
    const int cur = i & 1;
    if (i + 1 < nk) stage(cur ^ 1, (i + 1) * 32);

    bf16x8 af[MR], bfr[4];
#pragma unroll
    for (int m = 0; m < MR; ++m)
      af[m] = *reinterpret_cast<const bf16x8*>(&lA[cur][(wr + m * 16 + r16) * 32 + kg * 8]);
#pragma unroll
    for (int n = 0; n < 4; ++n)
      bfr[n] = *reinterpret_cast<const bf16x8*>(&lB[cur][(wc + n * 16 + r16) * 32 + kg * 8]);
#pragma unroll
    for (int m = 0; m < MR; ++m)
#pragma unroll
      for (int n = 0; n < 4; ++n)
        acc[m][n] = __builtin_amdgcn_mfma_f32_16x16x32_bf16(af[m], bfr[n], acc[m][n], 0, 0, 0);

    __syncthreads();  // drains lgkm (reads of cur) + vmcnt (stage of cur^1)
  }

#pragma unroll
  for (int m = 0; m < MR; ++m) {
    int row = bm + wr + m * 16 + kg * 4;
#pragma unroll
    for (int n = 0; n < 4; ++n) {
      int col = bn + wc + n * 16 + r16;
      float bv = bias[col];
#pragma unroll
      for (int j = 0; j < 4; ++j) {
        float v = acc[m][n][j] + bv;
        if (RELU) v = fmaxf(v, 0.f);
        if (OUTF32)
          Cf[(size_t)(row + j) * N + col] = v;
        else
          Cb[(size_t)(row + j) * N + col] = f2bf(v);
      }
    }
  }
}

// ---------------- V transpose via LDS: 64x64 tiles, coalesced both sides ----------------
__global__ __launch_bounds__(256) void vt_kern(const u16* __restrict__ src, int stride,
                                               int hmul, int hadd, u16* __restrict__ VT) {
  __shared__ u16 lt[64][72];
  const int bh = blockIdx.y;
  const int b = bh >> 4, h = bh & 15;
  const int s0 = blockIdx.x * 64;
  const u16* sb = src + (size_t)b * NS * stride + h * hmul + hadd;
#pragma unroll
  for (int c = 0; c < 2; ++c) {
    int chunk = c * 256 + threadIdx.x;
    int r = chunk >> 3, d = (chunk & 7) * 8;
    *reinterpret_cast<uint4*>(&lt[r][d]) =
        *reinterpret_cast<const uint4*>(&sb[(size_t)(s0 + r) * stride + d]);
  }
  __syncthreads();
  const int d = threadIdx.x >> 2, sq = (threadIdx.x & 3) * 16;
  union { u16 e[16]; uint4 v[2]; } pk;
#pragma unroll
  for (int i = 0; i < 16; ++i) pk.e[i] = lt[sq + i][d];
  uint4* dst = reinterpret_cast<uint4*>(&VT[((size_t)bh * NHD + d) * NS + s0 + sq]);
  dst[0] = pk.v[0];
  dst[1] = pk.v[1];
}

// ---------------- flash attention v4: 32 q-rows/wave + K-prefetch pipeline ----------------
// 512 blocks x 4 waves; barrier-free; swapped QK^T (lane col = q = r16).
// K frags double-buffered in registers; V issued before QK^T MFMAs (hides under compute).
#define LPP 72  // P row pitch (u16)
#define C1F 0.180336880f  // 0.125 * log2(e): softmax in exp2 domain

template <int CAUSAL>
__global__ __launch_bounds__(256, 2) void attn4(const u16* __restrict__ Qp, int qstride,
                                                int qhm, const u16* __restrict__ Kp,
                                                int kstride, int khm, int kha,
                                                const u16* __restrict__ VT,
                                                u16* __restrict__ O) {
  const int bid = blockIdx.x;              // 512
  const int xcd = bid & 7, j5 = bid >> 3;  // 0..63
  const int bh = xcd + 8 * (j5 >> 4);      // 4 bh per XCD (K/VT pinned in one L2)
  int qt = j5 & 15;
  if (CAUSAL) qt = 15 - qt;                // heavy q-tiles dispatch first
  const int b = bh >> 4, h = bh & 15;
  const int tid = threadIdx.x, lane = tid & 63, wave = tid >> 6;
  const int r16 = lane & 15, kg = lane >> 4;
  const int q0w = qt * 128 + wave * 32;

  __shared__ __align__(16) u16 lP[4][32 * LPP];  // wave-private P tiles
  u16* lPw = &lP[wave][0];

  const u16* qb = Qp + (size_t)b * NS * qstride + h * qhm;
  const u16* kb = Kp + (size_t)b * NS * kstride + h * khm + kha;
  const u16* vb = VT + (size_t)bh * NHD * NS;

  bf16x8 qf[2][2];
#pragma unroll
  for (int qn = 0; qn < 2; ++qn)
#pragma unroll
    for (int ks = 0; ks < 2; ++ks)
      qf[qn][ks] = *reinterpret_cast<const bf16x8*>(
          &qb[(size_t)(q0w + qn * 16 + r16) * qstride + ks * 32 + kg * 8]);

  f32x4 o_acc[2][4] = {};
  float m_run[2] = {-1e30f, -1e30f}, l_run[2] = {0.f, 0.f};
  bf16x8 kfA[8], kfB[8], vf[8];

  const int nt = CAUSAL ? (q0w / 64 + 1) : (NS / 64);

  auto loadK = [&](auto& dst, int kv0) {
#pragma unroll
    for (int c = 0; c < 4; ++c)
#pragma unroll
      for (int ks = 0; ks < 2; ++ks)
        dst[c * 2 + ks] = *reinterpret_cast<const bf16x8*>(
            &kb[(size_t)(kv0 + c * 16 + r16) * kstride + ks * 32 + kg * 8]);
  };

  auto tile = [&](auto& kf, auto& kn, int t, bool pre) {
    const int kv0 = t * 64;
    // V for this tile: issue first, consumed last (latency hides under QK+softmax)
#pragma unroll
    for (int cd = 0; cd < 4; ++cd)
#pragma unroll
      for (int ks = 0; ks < 2; ++ks)
        vf[cd * 2 + ks] = *reinterpret_cast<const bf16x8*>(
            &vb[(size_t)(cd * 16 + r16) * NS + kv0 + ks * 32 + kg * 8]);

    // S^T = K @ Q^T : 16 MFMAs (waits only on kf loads)
    f32x4 s[2][4] = {};
#pragma unroll
    for (int c = 0; c < 4; ++c)
#pragma unroll
      for (int ks = 0; ks < 2; ++ks) {
        s[0][c] = __builtin_amdgcn_mfma_f32_16x16x32_bf16(kf[c * 2 + ks], qf[0][ks], s[0][c], 0, 0, 0);
        s[1][c] = __builtin_amdgcn_mfma_f32_16x16x32_bf16(kf[c * 2 + ks], qf[1][ks], s[1][c], 0, 0, 0);
      }

    // prefetch next tile's K (overlaps softmax + PV)
    if (pre) loadK(kn, kv0 + 64);

    // online softmax per qn (exp2 domain; q = r16; rows kv in-register)
#pragma unroll
    for (int qn = 0; qn < 2; ++qn) {
      const int q = q0w + qn * 16 + r16;
#pragma unroll
      for (int c = 0; c < 4; ++c)
#pragma unroll
        for (int j = 0; j < 4; ++j) {
          float z = s[qn][c][j] * C1F;
          if (CAUSAL && t == nt - 1 && (kv0 + c * 16 + kg * 4 + j > q)) z = -1e30f;
          s[qn][c][j] = z;
        }
      float mx = -1e30f;
#pragma unroll
      for (int c = 0; c < 4; ++c)
#pragma unroll
        for (int j = 0; j < 4; ++j) mx = fmaxf(mx, s[qn][c][j]);
      mx = fmaxf(mx, __shfl_xor(mx, 16));
      mx = fmaxf(mx, __shfl_xor(mx, 32));

      float mn = m_run[qn];
      if (!__all(mx <= mn + 8.f)) {  // defer-max: skip rescale while P <= 2^8
        mn = fmaxf(mn, mx);
        const float cr = exp2f(m_run[qn] - mn);
        m_run[qn] = mn;
        l_run[qn] *= cr;
        float crow[4];
#pragma unroll
        for (int j = 0; j < 4; ++j) crow[j] = __shfl(cr, kg * 4 + j);
#pragma unroll
        for (int cd = 0; cd < 4; ++cd)
#pragma unroll
          for (int j = 0; j < 4; ++j) o_acc[qn][cd][j] *= crow[j];
      }

      float su = 0.f;
#pragma unroll
      for (int c = 0; c < 4; ++c)
#pragma unroll
        for (int j = 0; j < 4; ++j) {
          float p = exp2f(s[qn][c][j] - mn);
          s[qn][c][j] = p;
          su += p;
        }
      su += __shfl_xor(su, 16);
      su += __shfl_xor(su, 32);
      l_run[qn] += su;

      // P -> wave-private LDS (packed b32; no barrier)
#pragma unroll
      for (int c = 0; c < 4; ++c) {
        u32 u0 = (u32)f2bf(s[qn][c][0]) | ((u32)f2bf(s[qn][c][1]) << 16);
        u32 u1 = (u32)f2bf(s[qn][c][2]) | ((u32)f2bf(s[qn][c][3]) << 16);
        u16* row = &lPw[(qn * 16 + r16) * LPP + c * 16 + kg * 4];
        *reinterpret_cast<u32*>(row) = u0;
        *reinterpret_cast<u32*>(row + 2) = u1;
      }
    }

    // PV
    bf16x8 pf[2][2];
#pragma unroll
    for (int qn = 0; qn < 2; ++qn)
#pragma unroll
      for (int ks = 0; ks < 2; ++ks)
        pf[qn][ks] = *reinterpret_cast<const bf16x8*>(
            &lPw[(qn * 16 + r16) * LPP + ks * 32 + kg * 8]);
#pragma unroll
    for (int cd = 0; cd < 4; ++cd)
#pragma unroll
      for (int ks = 0; ks < 2; ++ks) {
        o_acc[0][cd] = __builtin_amdgcn_mfma_f32_16x16x32_bf16(pf[0][ks], vf[cd * 2 + ks],
                                                               o_acc[0][cd], 0, 0, 0);
        o_acc[1][cd] = __builtin_amdgcn_mfma_f32_16x16x32_bf16(pf[1][ks], vf[cd * 2 + ks],
                                                               o_acc[1][cd], 0, 0, 0);
      }
  };

  // pipelined loop: K frags double-buffered, 2 tiles per pass
  loadK(kfA, 0);
  int t = 0;
  while (true) {
    bool more = (t + 1 < nt);
    tile(kfA, kfB, t, more);
    if (!more) break;
    ++t;
    more = (t + 1 < nt);
    tile(kfB, kfA, t, more);
    if (!more) break;
    ++t;
  }

  // epilogue
#pragma unroll
  for (int qn = 0; qn < 2; ++qn) {
    float linv = 1.f / l_run[qn];
    float li[4];
#pragma unroll
    for (int j = 0; j < 4; ++j) li[j] = __shfl(linv, kg * 4 + j);
#pragma unroll
    for (int cd = 0; cd < 4; ++cd) {
      int col = h * NHD + cd * 16 + r16;
#pragma unroll
      for (int j = 0; j < 4; ++j) {
        int row = q0w + qn * 16 + kg * 4 + j;
        O[((size_t)b * NS + row) * ND + col] = f2bf(o_acc[qn][cd][j] * li[j]);
      }
    }
  }
}

// ---------------- fused residual + LayerNorm (writes f32 + bf16) ----------------
__global__ __launch_bounds__(256) void ln_kern(const float* __restrict__ a,
                                               const float* __restrict__ resid,
                                               const float* __restrict__ g,
                                               const float* __restrict__ bb,
                                               float* __restrict__ outf,
                                               u16* __restrict__ outb) {
  const int row = blockIdx.x;
  const int tid = threadIdx.x;
  const size_t off = (size_t)row * ND + tid * 4;
  f32x4 v = *reinterpret_cast<const f32x4*>(&a[off]);
  f32x4 r = *reinterpret_cast<const f32x4*>(&resid[off]);
#pragma unroll
  for (int j = 0; j < 4; ++j) v[j] += r[j];
  float s = v[0] + v[1] + v[2] + v[3];
  float s2 = v[0] * v[0] + v[1] * v[1] + v[2] * v[2] + v[3] * v[3];
#pragma unroll
  for (int m = 1; m < 64; m <<= 1) {
    s += __shfl_xor(s, m);
    s2 += __shfl_xor(s2, m);
  }
  __shared__ float ws1[4], ws2[4];
  int wave = tid >> 6, lane = tid & 63;
  if (lane == 0) { ws1[wave] = s; ws2[wave] = s2; }
  __syncthreads();
  s = ws1[0] + ws1[1] + ws1[2] + ws1[3];
  s2 = ws2[0] + ws2[1] + ws2[2] + ws2[3];
  float mean = s * (1.f / ND);
  float var = fmaxf(s2 * (1.f / ND) - mean * mean, 0.f);
  float rstd = rsqrtf(var + 1e-9f);
  f32x4 gg = *reinterpret_cast<const f32x4*>(&g[tid * 4]);
  f32x4 bv = *reinterpret_cast<const f32x4*>(&bb[tid * 4]);
  f32x4 o;
  u16x4 ob;
#pragma unroll
  for (int j = 0; j < 4; ++j) {
    o[j] = gg[j] * (v[j] - mean) * rstd + bv[j];
    ob[j] = f2bf(o[j]);
  }
  *reinterpret_cast<f32x4*>(&outf[off]) = o;
  *reinterpret_cast<u16x4*>(&outb[off]) = ob;
}

// ---------------- host launch ----------------
extern "C" void kernel_launch(void* const* d_in, const int* in_sizes, int n_in,
                              void* d_out, int out_size, void* d_ws, size_t ws_size,
                              hipStream_t stream) {
  const float* x = (const float*)d_in[0];
  const float* y = (const float*)d_in[1];
  const float* qkv_w = (const float*)d_in[3];
  const float* qkv_b = (const float*)d_in[4];
  const float* sa_fc_w = (const float*)d_in[5];
  const float* sa_fc_b = (const float*)d_in[6];
  const float* g1 = (const float*)d_in[7];
  const float* b1 = (const float*)d_in[8];
  const float* kv_w = (const float*)d_in[9];
  const float* kv_b = (const float*)d_in[10];
  const float* q_w = (const float*)d_in[11];
  const float* q_b = (const float*)d_in[12];
  const float* ca_fc_w = (const float*)d_in[13];
  const float* ca_fc_b = (const float*)d_in[14];
  const float* g2 = (const float*)d_in[15];
  const float* b2 = (const float*)d_in[16];
  const float* ff1_w = (const float*)d_in[17];
  const float* ff1_b = (const float*)d_in[18];
  const float* ff2_w = (const float*)d_in[19];
  const float* ff2_b = (const float*)d_in[20];
  const float* g3 = (const float*)d_in[21];
  const float* b3 = (const float*)d_in[22];

  if (ws_size < (120ull << 20)) return;

  char* w = (char*)d_ws;
  u16* W16 = (u16*)(w + 0);              // 8 MB
  u16* ACT = (u16*)(w + (8ull << 20));   // 8 MB
  u16* XB  = (u16*)(w + (16ull << 20));  // 8 MB
  u16* Qb  = (u16*)(w + (24ull << 20));  // 8 MB (cross-attn Q gemm out)
  u16* VT  = (u16*)(w + (40ull << 20));  // 8 MB (V transposed [bh][64][S])
  u16* AO  = (u16*)(w + (48ull << 20));  // 8 MB attention out
  u16* G   = (u16*)(w + (56ull << 20));  // 24 MB big GEMM out
  float* Fa = (float*)(w + (88ull << 20));   // 16 MB
  float* Fb = (float*)(w + (104ull << 20));  // 16 MB
  float* OUT = (float*)d_out;

  dim3 wblk(32, 8);
  const int n4act = NBS * ND / 4;

  // ---- self attention block ----
  conv_bf16<<<n4act / 256, 256, 0, stream>>>(y, ACT, n4act);
  wconv_t<<<dim3(3 * ND / 32, ND / 32), wblk, 0, stream>>>(qkv_w, W16, ND, 3 * ND);
  gemm_bt<128, 0, 0><<<dim3(3 * ND / 128, NBS / 128), 256, 0, stream>>>(
      ACT, W16, qkv_b, nullptr, G, NBS, 3 * ND, ND);
  vt_kern<<<dim3(NS / 64, NB * NH), 256, 0, stream>>>(G, 3 * ND, 192, 128, VT);
  attn4<1><<<512, 256, 0, stream>>>(G, 3 * ND, 192, G, 3 * ND, 192, 64, VT, AO);
  wconv_t<<<dim3(ND / 32, ND / 32), wblk, 0, stream>>>(sa_fc_w, W16, ND, ND);
  gemm_bt<64, 1, 0><<<dim3(ND / 128, NBS / 64), 256, 0, stream>>>(
      AO, W16, sa_fc_b, Fa, nullptr, NBS, ND, ND);
  ln_kern<<<NBS, 256, 0, stream>>>(Fa, y, g1, b1, Fb, ACT);  // y1

  // ---- cross attention block ----
  conv_bf16<<<n4act / 256, 256, 0, stream>>>(x, XB, n4act);
  wconv_t<<<dim3(2 * ND / 32, ND / 32), wblk, 0, stream>>>(kv_w, W16, ND, 2 * ND);
  gemm_bt<128, 0, 0><<<dim3(2 * ND / 128, NBS / 128), 256, 0, stream>>>(
      XB, W16, kv_b, nullptr, G, NBS, 2 * ND, ND);
  vt_kern<<<dim3(NS / 64, NB * NH), 256, 0, stream>>>(G, 2 * ND, 128, 64, VT);
  wconv_t<<<dim3(ND / 32, ND / 32), wblk, 0, stream>>>(q_w, W16, ND, ND);
  gemm_bt<64, 0, 0><<<dim3(ND / 128, NBS / 64), 256, 0, stream>>>(
      ACT, W16, q_b, nullptr, Qb, NBS, ND, ND);
  attn4<0><<<512, 256, 0, stream>>>(Qb, ND, 64, G, 2 * ND, 128, 0, VT, AO);
  wconv_t<<<dim3(ND / 32, ND / 32), wblk, 0, stream>>>(ca_fc_w, W16, ND, ND);
  gemm_bt<64, 1, 0><<<dim3(ND / 128, NBS / 64), 256, 0, stream>>>(
      AO, W16, ca_fc_b, Fa, nullptr, NBS, ND, ND);
  ln_kern<<<NBS, 256, 0, stream>>>(Fa, Fb, g2, b2, Fb, ACT);  // y2

  // ---- FFN ----
  wconv_t<<<dim3(NFF / 32, ND / 32), wblk, 0, stream>>>(ff1_w, W16, ND, NFF);
  gemm_bt<128, 0, 1><<<dim3(NFF / 128, NBS / 128), 256, 0, stream>>>(
      ACT, W16, ff1_b, nullptr, G, NBS, NFF, ND);
  wconv_t<<<dim3(ND / 32, NFF / 32), wblk, 0, stream>>>(ff2_w, W16, NFF, ND);
  gemm_bt<64, 1, 0><<<dim3(ND / 128, NBS / 64), 256, 0, stream>>>(
      G, W16, ff2_b, Fa, nullptr, NBS, ND, NFF);
  ln_kern<<<NBS, 256, 0, stream>>>(Fa, Fb, g3, b3, OUT, ACT);
}